// Round 7
// baseline (1326.608 us; speedup 1.0000x reference)
//
#include <hip/hip_runtime.h>
#include <stdint.h>

typedef unsigned char u8;
typedef unsigned short us;
typedef unsigned int u32;

#define CDIM  128
#define KNBR  48
#define HEADS 8
#define DHEAD 16
#define FFDIM 256

using bf16x8 = __attribute__((ext_vector_type(8))) short;  // 8 bf16 (4 VGPRs)
using f32x4  = __attribute__((ext_vector_type(4))) float;  // 4 fp32

__device__ inline float blo32(u32 u) { union { u32 i; float f; } v; v.i = u << 16; return v.f; }
__device__ inline float bhi32(u32 u) { union { u32 i; float f; } v; v.i = u & 0xFFFF0000u; return v.f; }
__device__ inline float bf2f(us u) { union { u32 i; float f; } v; v.i = ((u32)u) << 16; return v.f; }
__device__ inline us f2bf(float x) {
    union { float f; u32 i; } v; v.f = x;
    u32 r = v.i + 0x7FFFu + ((v.i >> 16) & 1u);
    return (us)(r >> 16);
}

// ---------------------------------------------------------------------------
// K0: probe key_mask storage (int32 vs u8 bool). flag=1 -> u8 storage.
// ---------------------------------------------------------------------------
__global__ void k_mask_probe(const u32* __restrict__ mw, int nwords,
                             int* __restrict__ flag)
{
    u32 any = 0;
    for (int j = blockIdx.x * blockDim.x + threadIdx.x; j < nwords;
         j += gridDim.x * blockDim.x)
        any |= mw[j] & 0xFFFFFF00u;
    if (any) atomicOr(flag, 1);
}

// ---------------------------------------------------------------------------
// K1: QKV projection. Q f32; Fk/Fv emitted bf16 (halves gather traffic).
// ---------------------------------------------------------------------------
__global__ __launch_bounds__(384) void k_qkv(
    const float* __restrict__ F, const float* __restrict__ W,
    const float* __restrict__ B,
    float* __restrict__ Q, us* __restrict__ FkB, us* __restrict__ FvB, int N)
{
    __shared__ float xL[8][CDIM];
    int row0 = blockIdx.x * 8;
    int t = threadIdx.x;
    for (int o = t; o < 8 * CDIM; o += 384) {
        int r = o >> 7, c = o & 127;
        int row = row0 + r;
        xL[r][c] = (row < N) ? F[row * CDIM + c] : 0.f;
    }
    __syncthreads();

    int e = t;  // 0..383
    const float4* W4 = (const float4*)(W + e * CDIM);
    float acc[8] = {0.f,0.f,0.f,0.f,0.f,0.f,0.f,0.f};
    #pragma unroll 8
    for (int c4 = 0; c4 < CDIM / 4; ++c4) {
        float4 w = W4[c4];
        #pragma unroll
        for (int r = 0; r < 8; ++r) {
            const float* x = &xL[r][c4 * 4];
            acc[r] += x[0]*w.x + x[1]*w.y + x[2]*w.z + x[3]*w.w;
        }
    }
    float bv = B[e];
    if (e < 128) {
        #pragma unroll
        for (int r = 0; r < 8; ++r) {
            int row = row0 + r;
            if (row < N) Q[row * CDIM + e] = acc[r] + bv;
        }
    } else if (e < 256) {
        int eo = e - 128;
        #pragma unroll
        for (int r = 0; r < 8; ++r) {
            int row = row0 + r;
            if (row < N) FkB[(size_t)row * CDIM + eo] = f2bf(acc[r] + bv);
        }
    } else {
        int eo = e - 256;
        #pragma unroll
        for (int r = 0; r < 8; ++r) {
            int row = row0 + r;
            if (row < N) FvB[(size_t)row * CDIM + eo] = f2bf(acc[r] + bv);
        }
    }
}

// ---------------------------------------------------------------------------
// K2: attention, one block (256 thr = 4 waves) per query voxel.
// Scores: MFMA qw(hi/lo).P(hi/lo in regs) + f32 q.Fk (wave 3, bf16 gather).
// Pbar:   MFMA attn(hi/lo from scL).P-hi REBUILT in registers in B-fragment
//         layout (P is 3 FMA/elem from rel&kpw — cheaper than LDS transpose).
// No P plane in LDS at all. LDS 14656 B -> 6 blocks/CU (75% cap).
// ---------------------------------------------------------------------------
__global__ __launch_bounds__(256, 6) void k_attn(
    const float* __restrict__ coords, const int* __restrict__ kidx,
    const u8* __restrict__ kmask_u8, const int* __restrict__ kmask_i32,
    const int* __restrict__ maskflag,
    const float* __restrict__ Q, const us* __restrict__ FkB,
    const us* __restrict__ FvB,
    const float* __restrict__ wk, const float* __restrict__ wv,
    const float* __restrict__ kpw, const float* __restrict__ kpb,
    float* __restrict__ CTX)
{
    // manual LDS layout (bytes):
    __shared__ __align__(16) u8 SM[14656];
    us*    qwH   = (us*)(SM);             // [8][136]  qw hi       (2176)
    us*    qwL   = (us*)(SM + 2176);      // [8][136]  qw lo       (2176)
    float* scL   = (float*)(SM + 4352);   // [8][52]               (1664)
    float* Ql    = (float*)(SM + 6016);   // [128]                 (512)
    float* rel   = (float*)(SM + 6528);   // [48][3]               (576)
    float* kpw0S = (float*)(SM + 7104);   // [128]                 (512)
    float* kpw1S = (float*)(SM + 7616);   // [128]                 (512)
    float* kpw2S = (float*)(SM + 8128);   // [128]                 (512)
    float* kpbS  = (float*)(SM + 8640);   // [128]                 (512)
    int*   idxl  = (int*)  (SM + 9152);   // [48]                  (192)
    u8*    mskl  = (u8*)   (SM + 9344);   // [48] (pad 64)         (64)
    float* Pb    = (float*)(SM + 9408);   // [8][132] Pbar         (4224)
    float* pc    = (float*)(SM + 13632);  // [2][128]              (1024)

    int n = blockIdx.x;
    int t = threadIdx.x;
    int w = t >> 6, lane = t & 63;

    // ---- phase A: indices / mask / rel / q row / kpw staging (transposed) ----
    if (t < KNBR) {
        int idx = kidx[n * KNBR + t];
        idxl[t] = idx;
        mskl[t] = maskflag[0] ? kmask_u8[n * KNBR + t]
                              : (u8)kmask_i32[n * KNBR + t];
        rel[t * 3 + 0] = coords[idx * 3 + 0] - coords[n * 3 + 0];
        rel[t * 3 + 1] = coords[idx * 3 + 1] - coords[n * 3 + 1];
        rel[t * 3 + 2] = coords[idx * 3 + 2] - coords[n * 3 + 2];
    }
    if (t < 128) {
        kpw0S[t] = kpw[t * 3 + 0];
        kpw1S[t] = kpw[t * 3 + 1];
        kpw2S[t] = kpw[t * 3 + 2];
        kpbS[t]  = kpb[t];
    } else {
        Ql[t - 128] = Q[n * CDIM + (t - 128)];
    }
    __syncthreads();

    // ---- phase B1: qw = q_h @ wk_h (f32 -> hi/lo bf16 in LDS, 8 rows) ----
    {
        int h = t >> 5, c4 = t & 31;
        const float* qh = Ql + h * DHEAD;
        float a0=0.f, a1=0.f, a2=0.f, a3=0.f;
        #pragma unroll
        for (int d = 0; d < DHEAD; ++d) {
            float q = qh[d];
            float4 wr = *(const float4*)(wk + (size_t)(h * DHEAD + d) * CDIM + c4 * 4);
            a0 += q * wr.x; a1 += q * wr.y; a2 += q * wr.z; a3 += q * wr.w;
        }
        us h0=f2bf(a0), h1=f2bf(a1), h2=f2bf(a2), h3=f2bf(a3);
        us l0=f2bf(a0-bf2f(h0)), l1=f2bf(a1-bf2f(h1)),
           l2=f2bf(a2-bf2f(h2)), l3=f2bf(a3-bf2f(h3));
        uint2 ph; ph.x = (u32)h0 | ((u32)h1 << 16); ph.y = (u32)h2 | ((u32)h3 << 16);
        uint2 pl; pl.x = (u32)l0 | ((u32)l1 << 16); pl.y = (u32)l2 | ((u32)l3 << 16);
        *(uint2*)&qwH[h * 136 + c4 * 4] = ph;
        *(uint2*)&qwL[h * 136 + c4 * 4] = pl;
    }

    // ---- phase B2: waves 0-2: P score-B-fragments in registers;
    //                wave 3: exact f32 q.Fk partial scores (bf16 gather) ----
    union U8 { bf16x8 v; u32 wd[4]; };
    U8 BH[4], BL[4];
    if (w < 3) {
        int kk = w * 16 + (lane & 15);        // P row this lane owns
        int cb0 = (lane >> 4) * 8;            // c-chunk base
        float r0 = rel[kk * 3], r1 = rel[kk * 3 + 1], r2 = rel[kk * 3 + 2];
        #pragma unroll
        for (int s = 0; s < 4; ++s) {
            int cb = cb0 + s * 32;
            float4 x0 = *(const float4*)&kpw0S[cb], x1 = *(const float4*)&kpw0S[cb + 4];
            float4 y0 = *(const float4*)&kpw1S[cb], y1 = *(const float4*)&kpw1S[cb + 4];
            float4 z0 = *(const float4*)&kpw2S[cb], z1 = *(const float4*)&kpw2S[cb + 4];
            float4 b0 = *(const float4*)&kpbS[cb],  b1 = *(const float4*)&kpbS[cb + 4];
            float p[8];
            p[0] = fmaxf(b0.x + r0*x0.x + r1*y0.x + r2*z0.x, 0.f);
            p[1] = fmaxf(b0.y + r0*x0.y + r1*y0.y + r2*z0.y, 0.f);
            p[2] = fmaxf(b0.z + r0*x0.z + r1*y0.z + r2*z0.z, 0.f);
            p[3] = fmaxf(b0.w + r0*x0.w + r1*y0.w + r2*z0.w, 0.f);
            p[4] = fmaxf(b1.x + r0*x1.x + r1*y1.x + r2*z1.x, 0.f);
            p[5] = fmaxf(b1.y + r0*x1.y + r1*y1.y + r2*z1.y, 0.f);
            p[6] = fmaxf(b1.z + r0*x1.z + r1*y1.z + r2*z1.z, 0.f);
            p[7] = fmaxf(b1.w + r0*x1.w + r1*y1.w + r2*z1.w, 0.f);
            #pragma unroll
            for (int j = 0; j < 4; ++j) {
                us hA = f2bf(p[2*j]), hB = f2bf(p[2*j+1]);
                BH[s].wd[j] = (u32)hA | ((u32)hB << 16);
                us lA = f2bf(p[2*j]   - bf2f(hA));
                us lB = f2bf(p[2*j+1] - bf2f(hB));
                BL[s].wd[j] = (u32)lA | ((u32)lB << 16);
            }
        }
    } else {
        #pragma unroll
        for (int i = 0; i < 6; ++i) {
            int o = lane * 6 + i;             // 384 = 48 k x 8 h
            int k = o >> 3, h = o & 7;
            const float* qh = Ql + h * DHEAD;
            const uint4* fk = (const uint4*)(FkB + (size_t)idxl[k] * CDIM + h * DHEAD);
            uint4 fa = fk[0], fb = fk[1];
            float s = qh[0]*blo32(fa.x) + qh[1]*bhi32(fa.x)
                    + qh[2]*blo32(fa.y) + qh[3]*bhi32(fa.y)
                    + qh[4]*blo32(fa.z) + qh[5]*bhi32(fa.z)
                    + qh[6]*blo32(fa.w) + qh[7]*bhi32(fa.w)
                    + qh[8]*blo32(fb.x) + qh[9]*bhi32(fb.x)
                    + qh[10]*blo32(fb.y) + qh[11]*bhi32(fb.y)
                    + qh[12]*blo32(fb.z) + qh[13]*bhi32(fb.z)
                    + qh[14]*blo32(fb.w) + qh[15]*bhi32(fb.w);
            scL[h * 52 + k] = s;
        }
    }
    __syncthreads();

    // ---- phase C: MFMA scores (waves 0-2), A=qw from LDS (rows>=8 zero) ----
    if (w < 3) {
        f32x4 acc = {0.f, 0.f, 0.f, 0.f};
        int arow = lane & 15;
        int ko = (lane >> 4) * 8;
        bool aval = arow < 8;
        bf16x8 zz = {0,0,0,0,0,0,0,0};
        #pragma unroll
        for (int s = 0; s < 4; ++s) {
            int c0 = s * 32 + ko;
            bf16x8 ah = aval ? *(const bf16x8*)(qwH + arow * 136 + c0) : zz;
            bf16x8 al = aval ? *(const bf16x8*)(qwL + arow * 136 + c0) : zz;
            acc = __builtin_amdgcn_mfma_f32_16x16x32_bf16(ah, BH[s].v, acc, 0, 0, 0);
            acc = __builtin_amdgcn_mfma_f32_16x16x32_bf16(ah, BL[s].v, acc, 0, 0, 0);
            acc = __builtin_amdgcn_mfma_f32_16x16x32_bf16(al, BH[s].v, acc, 0, 0, 0);
        }
        // combine: D col=lane&15 -> kk, row=(lane>>4)*4+j -> h (rows 0-7 valid)
        if (lane < 32) {
            int kk = w * 16 + (lane & 15);
            int rb = (lane >> 4) * 4;
            u8 mk = mskl[kk];
            #pragma unroll
            for (int j = 0; j < 4; ++j) {
                int h = rb + j;
                float s = acc[j] + scL[h * 52 + kk];
                scL[h * 52 + kk] = mk ? -1e30f : s * 0.25f;
            }
        }
    }
    __syncthreads();

    // ---- phase D: softmax (32 lanes per head) ----
    {
        int h = t >> 5, l32 = t & 31;
        float* sc = scL + h * 52;
        float v0 = sc[l32];
        float v1 = (l32 < KNBR - 32) ? sc[l32 + 32] : -1e30f;
        float m = fmaxf(v0, v1);
        #pragma unroll
        for (int off = 16; off >= 1; off >>= 1)
            m = fmaxf(m, __shfl_xor(m, off, 32));
        float e0 = __expf(v0 - m);
        float e1 = (l32 < KNBR - 32) ? __expf(v1 - m) : 0.f;
        float s = e0 + e1;
        #pragma unroll
        for (int off = 16; off >= 1; off >>= 1)
            s += __shfl_xor(s, off, 32);
        float inv = 1.f / s;
        sc[l32] = e0 * inv;
        if (l32 < KNBR - 32) sc[l32 + 32] = e1 * inv;
    }
    __syncthreads();

    // ---- phase E: Pbar via MFMA. A=attn hi/lo (from scL), B=P-hi rebuilt
    //      in registers in B-fragment layout. All 4 waves, 2 c-tiles each. ----
    {
        bf16x8 AH[2], AL[2];
        int arow = lane & 15;
        bool av = arow < 8;
        #pragma unroll
        for (int st = 0; st < 2; ++st) {
            int k0 = (lane >> 4) * 8 + st * 32;
            float pr[8];
            if (av && k0 < KNBR) {
                float4 s0 = *(const float4*)&scL[arow * 52 + k0];
                float4 s1 = *(const float4*)&scL[arow * 52 + k0 + 4];
                pr[0]=s0.x; pr[1]=s0.y; pr[2]=s0.z; pr[3]=s0.w;
                pr[4]=s1.x; pr[5]=s1.y; pr[6]=s1.z; pr[7]=s1.w;
            } else {
                #pragma unroll
                for (int j = 0; j < 8; ++j) pr[j] = 0.f;
            }
            U8 ah, al;
            #pragma unroll
            for (int j = 0; j < 4; ++j) {
                us hA = f2bf(pr[2*j]), hB = f2bf(pr[2*j+1]);
                ah.wd[j] = (u32)hA | ((u32)hB << 16);
                us lA = f2bf(pr[2*j]   - bf2f(hA));
                us lB = f2bf(pr[2*j+1] - bf2f(hB));
                al.wd[j] = (u32)lA | ((u32)lB << 16);
            }
            AH[st] = ah.v; AL[st] = al.v;
        }
        #pragma unroll
        for (int ct = 0; ct < 2; ++ct) {
            int c = w * 32 + ct * 16 + (lane & 15);
            float w0 = kpw0S[c], w1 = kpw1S[c], w2 = kpw2S[c], bb = kpbS[c];
            f32x4 acc = {0.f, 0.f, 0.f, 0.f};
            #pragma unroll
            for (int st = 0; st < 2; ++st) {
                int k0 = (lane >> 4) * 8 + st * 32;
                U8 bh;
                if (k0 < KNBR) {
                    #pragma unroll
                    for (int j = 0; j < 4; ++j) {
                        const float* ra = rel + (k0 + 2*j) * 3;
                        const float* rb = rel + (k0 + 2*j + 1) * 3;
                        float pa = fmaxf(bb + ra[0]*w0 + ra[1]*w1 + ra[2]*w2, 0.f);
                        float pb = fmaxf(bb + rb[0]*w0 + rb[1]*w1 + rb[2]*w2, 0.f);
                        bh.wd[j] = (u32)f2bf(pa) | ((u32)f2bf(pb) << 16);
                    }
                } else {
                    bh.wd[0]=bh.wd[1]=bh.wd[2]=bh.wd[3]=0u;
                }
                acc = __builtin_amdgcn_mfma_f32_16x16x32_bf16(AH[st], bh.v, acc, 0, 0, 0);
                acc = __builtin_amdgcn_mfma_f32_16x16x32_bf16(AL[st], bh.v, acc, 0, 0, 0);
            }
            // D: col=lane&15 (c), row=(lane>>4)*4+j (h; rows 0-7 valid)
            if (lane < 32) {
                int rb2 = (lane >> 4) * 4;
                #pragma unroll
                for (int j = 0; j < 4; ++j)
                    Pb[(rb2 + j) * 132 + c] = acc[j];
            }
        }
    }
    __syncthreads();

    // ---- phase F: ctx = attn @ Fv (bf16 gather) + Pbar . wv ----
    {
        int c = t & 127, half = t >> 7;
        int h = c >> 4;
        const float* sc = scL + h * 52;
        float accF = 0.f;
        #pragma unroll 4
        for (int kk = 0; kk < 24; ++kk) {
            int k = half * 24 + kk;
            accF += sc[k] * bf2f(FvB[(size_t)idxl[k] * CDIM + c]);
        }
        const float4* wr = (const float4*)(wv + (size_t)c * CDIM) + half * 16;
        const float4* pb4 = (const float4*)(Pb + h * 132) + half * 16;
        #pragma unroll 4
        for (int j = 0; j < 16; ++j) {
            float4 wq = wr[j], p = pb4[j];
            accF += wq.x*p.x + wq.y*p.y + wq.z*p.z + wq.w*p.w;
        }
        pc[half * 128 + c] = accF;
    }
    __syncthreads();
    if (t < CDIM) CTX[n * CDIM + t] = pc[t] + pc[128 + t];
}

// ---------------------------------------------------------------------------
// K3/K6: 128->128 GEMM + bias (+ optional residual) + LayerNorm (+ opt relu)
// ---------------------------------------------------------------------------
__global__ __launch_bounds__(256) void k_proj_ln(
    const float* __restrict__ X, const float* __restrict__ RES,
    const float* __restrict__ W, const float* __restrict__ B,
    const float* __restrict__ G, const float* __restrict__ LB,
    float* __restrict__ OUT, int N, int relu_out)
{
    __shared__ float xL[16][CDIM];
    __shared__ float aL[16][CDIM + 4];
    __shared__ float mu[16], rs[16];
    int row0 = blockIdx.x * 16;
    int t = threadIdx.x;
    for (int o = t; o < 16 * CDIM; o += 256) {
        int r = o >> 7, c = o & 127;
        int row = row0 + r;
        xL[r][c] = (row < N) ? X[row * CDIM + c] : 0.f;
    }
    __syncthreads();

    int e = t & 127, rh = t >> 7;
    const float4* W4 = (const float4*)(W + e * CDIM);
    float acc[8] = {0.f,0.f,0.f,0.f,0.f,0.f,0.f,0.f};
    #pragma unroll 8
    for (int c4 = 0; c4 < CDIM / 4; ++c4) {
        float4 w = W4[c4];
        #pragma unroll
        for (int i = 0; i < 8; ++i) {
            const float* x = &xL[rh * 8 + i][c4 * 4];
            acc[i] += x[0]*w.x + x[1]*w.y + x[2]*w.z + x[3]*w.w;
        }
    }
    float bv = B[e];
    #pragma unroll
    for (int i = 0; i < 8; ++i) {
        int r = rh * 8 + i, row = row0 + r;
        float a = acc[i] + bv;
        if (RES != nullptr && row < N) a += RES[row * CDIM + e];
        aL[r][e] = a;
    }
    __syncthreads();

    {
        int r = t >> 4, j = t & 15;
        float s = 0.f;
        #pragma unroll
        for (int jj = 0; jj < 8; ++jj) s += aL[r][j * 8 + jj];
        #pragma unroll
        for (int off = 8; off >= 1; off >>= 1) s += __shfl_xor(s, off, 16);
        float mean = s * (1.f / 128.f);
        float v = 0.f;
        #pragma unroll
        for (int jj = 0; jj < 8; ++jj) {
            float d = aL[r][j * 8 + jj] - mean; v += d * d;
        }
        #pragma unroll
        for (int off = 8; off >= 1; off >>= 1) v += __shfl_xor(v, off, 16);
        if (j == 0) { mu[r] = mean; rs[r] = rsqrtf(v * (1.f / 128.f) + 1e-5f); }
    }
    __syncthreads();

    for (int o = t; o < 16 * CDIM; o += 256) {
        int r = o >> 7, c = o & 127;
        int row = row0 + r;
        if (row < N) {
            float y = (aL[r][c] - mu[r]) * rs[r] * G[c] + LB[c];
            if (relu_out) y = fmaxf(y, 0.f);
            OUT[row * CDIM + c] = y;
        }
    }
}

// ---------------------------------------------------------------------------
// K4: ff1: hid = relu(x1 @ W1^T + b1), 128 -> 256.
// ---------------------------------------------------------------------------
__global__ __launch_bounds__(256) void k_ff1(
    const float* __restrict__ X, const float* __restrict__ W,
    const float* __restrict__ B, float* __restrict__ HID, int N)
{
    __shared__ float xL[8][CDIM];
    int row0 = blockIdx.x * 8;
    int t = threadIdx.x;
    for (int o = t; o < 8 * CDIM; o += 256) {
        int r = o >> 7, c = o & 127;
        int row = row0 + r;
        xL[r][c] = (row < N) ? X[row * CDIM + c] : 0.f;
    }
    __syncthreads();

    int e = t;
    const float4* W4 = (const float4*)(W + e * CDIM);
    float acc[8] = {0.f,0.f,0.f,0.f,0.f,0.f,0.f,0.f};
    #pragma unroll 8
    for (int c4 = 0; c4 < CDIM / 4; ++c4) {
        float4 w = W4[c4];
        #pragma unroll
        for (int r = 0; r < 8; ++r) {
            const float* x = &xL[r][c4 * 4];
            acc[r] += x[0]*w.x + x[1]*w.y + x[2]*w.z + x[3]*w.w;
        }
    }
    float bv = B[e];
    #pragma unroll
    for (int r = 0; r < 8; ++r) {
        int row = row0 + r;
        if (row < N) HID[row * FFDIM + e] = fmaxf(acc[r] + bv, 0.f);
    }
}

// ---------------------------------------------------------------------------
// K5: x2 = LN(x1 + hid @ W2^T + b2), 256 -> 128.
// ---------------------------------------------------------------------------
__global__ __launch_bounds__(256) void k_ff2_ln(
    const float* __restrict__ HID, const float* __restrict__ RES,
    const float* __restrict__ W, const float* __restrict__ B,
    const float* __restrict__ G, const float* __restrict__ LB,
    float* __restrict__ OUT, int N)
{
    __shared__ float xL[16][FFDIM];
    __shared__ float aL[16][CDIM + 4];
    __shared__ float mu[16], rs[16];
    int row0 = blockIdx.x * 16;
    int t = threadIdx.x;
    for (int o = t; o < 16 * FFDIM; o += 256) {
        int r = o >> 8, c = o & 255;
        int row = row0 + r;
        xL[r][c] = (row < N) ? HID[row * FFDIM + c] : 0.f;
    }
    __syncthreads();

    int e = t & 127, rh = t >> 7;
    const float4* W4 = (const float4*)(W + e * FFDIM);
    float acc[8] = {0.f,0.f,0.f,0.f,0.f,0.f,0.f,0.f};
    #pragma unroll 8
    for (int c4 = 0; c4 < FFDIM / 4; ++c4) {
        float4 w = W4[c4];
        #pragma unroll
        for (int i = 0; i < 8; ++i) {
            const float* x = &xL[rh * 8 + i][c4 * 4];
            acc[i] += x[0]*w.x + x[1]*w.y + x[2]*w.z + x[3]*w.w;
        }
    }
    float bv = B[e];
    #pragma unroll
    for (int i = 0; i < 8; ++i) {
        int r = rh * 8 + i, row = row0 + r;
        float a = acc[i] + bv;
        if (row < N) a += RES[row * CDIM + e];
        aL[r][e] = a;
    }
    __syncthreads();

    {
        int r = t >> 4, j = t & 15;
        float s = 0.f;
        #pragma unroll
        for (int jj = 0; jj < 8; ++jj) s += aL[r][j * 8 + jj];
        #pragma unroll
        for (int off = 8; off >= 1; off >>= 1) s += __shfl_xor(s, off, 16);
        float mean = s * (1.f / 128.f);
        float v = 0.f;
        #pragma unroll
        for (int jj = 0; jj < 8; ++jj) {
            float d = aL[r][j * 8 + jj] - mean; v += d * d;
        }
        #pragma unroll
        for (int off = 8; off >= 1; off >>= 1) v += __shfl_xor(v, off, 16);
        if (j == 0) { mu[r] = mean; rs[r] = rsqrtf(v * (1.f / 128.f) + 1e-5f); }
    }
    __syncthreads();

    for (int o = t; o < 16 * CDIM; o += 256) {
        int r = o >> 7, c = o & 127;
        int row = row0 + r;
        if (row < N)
            OUT[row * CDIM + c] = (aL[r][c] - mu[r]) * rs[r] * G[c] + LB[c];
    }
}

// ---------------------------------------------------------------------------
extern "C" void kernel_launch(void* const* d_in, const int* in_sizes, int n_in,
                              void* d_out, int out_size, void* d_ws, size_t ws_size,
                              hipStream_t stream)
{
    const float* F      = (const float*)d_in[0];
    const float* coords = (const float*)d_in[1];
    const int*   kidx   = (const int*)d_in[2];
    const void*  kmask  = d_in[3];
    const float* ipw    = (const float*)d_in[4];
    const float* ipb    = (const float*)d_in[5];
    const float* opw    = (const float*)d_in[6];
    const float* opb    = (const float*)d_in[7];
    const float* kpw    = (const float*)d_in[8];
    const float* kpb    = (const float*)d_in[9];
    const float* ln1g   = (const float*)d_in[10];
    const float* ln1b   = (const float*)d_in[11];
    const float* ln2g   = (const float*)d_in[12];
    const float* ln2b   = (const float*)d_in[13];
    const float* w1     = (const float*)d_in[14];
    const float* b1     = (const float*)d_in[15];
    const float* w2     = (const float*)d_in[16];
    const float* b2     = (const float*)d_in[17];
    const float* ow     = (const float*)d_in[18];
    const float* ob     = (const float*)d_in[19];
    const float* ln3g   = (const float*)d_in[20];
    const float* ln3b   = (const float*)d_in[21];

    int N = in_sizes[0] / CDIM;
    size_t NC = (size_t)N * CDIM;

    float* ws  = (float*)d_ws;
    // layout (floats):
    //   [0,   NC)   Q  (later X1)
    //   [NC,  1.5NC) FkB (bf16)  } HID = [NC,3NC) after attention
    //   [1.5NC,2NC)  FvB (bf16)  }
    //   [2NC, 3NC)  CTX (dead after proj_ln1)
    //   [3NC, 4NC)  X2
    //   [4NC]       mflag
    float* Q    = ws;
    us*    FkB  = (us*)(ws + NC);
    us*    FvB  = (us*)(ws + NC) + NC;
    float* CTX  = ws + 2 * NC;
    float* X1   = Q;
    float* HID  = ws + NC;
    float* X2   = ws + 3 * NC;
    int*   mflag = (int*)(ws + 4 * NC);

    const float* wk = ipw + CDIM * CDIM;
    const float* wv = ipw + 2 * CDIM * CDIM;

    hipMemsetAsync(mflag, 0, sizeof(int), stream);
    int nwords = (N * KNBR) / 4;
    k_mask_probe<<<256, 256, 0, stream>>>((const u32*)kmask, nwords, mflag);

    k_qkv<<<(N + 7) / 8, 384, 0, stream>>>(F, ipw, ipb, Q, FkB, FvB, N);
    k_attn<<<N, 256, 0, stream>>>(coords, kidx, (const u8*)kmask,
                                  (const int*)kmask, mflag, Q, FkB, FvB,
                                  wk, wv, kpw, kpb, CTX);
    k_proj_ln<<<(N + 15) / 16, 256, 0, stream>>>(CTX, F, opw, opb,
                                                 ln1g, ln1b, X1, N, 0);
    k_ff1<<<(N + 7) / 8, 256, 0, stream>>>(X1, w1, b1, HID, N);
    k_ff2_ln<<<(N + 15) / 16, 256, 0, stream>>>(HID, X1, w2, b2,
                                                ln2g, ln2b, X2, N);
    k_proj_ln<<<(N + 15) / 16, 256, 0, stream>>>(X2, nullptr, ow, ob,
                                                 ln3g, ln3b, (float*)d_out, N, 1);
}

// Round 8
// 1155.876 us; speedup vs baseline: 1.1477x; 1.1477x over previous
//
#include <hip/hip_runtime.h>
#include <stdint.h>

typedef unsigned char u8;
typedef unsigned short us;
typedef unsigned int u32;

#define CDIM  128
#define KNBR  48
#define HEADS 8
#define DHEAD 16
#define FFDIM 256

using bf16x8 = __attribute__((ext_vector_type(8))) short;  // 8 bf16 (4 VGPRs)
using f32x4  = __attribute__((ext_vector_type(4))) float;  // 4 fp32

__device__ inline float blo32(u32 u) { union { u32 i; float f; } v; v.i = u << 16; return v.f; }
__device__ inline float bhi32(u32 u) { union { u32 i; float f; } v; v.i = u & 0xFFFF0000u; return v.f; }
__device__ inline float bf2f(us u) { union { u32 i; float f; } v; v.i = ((u32)u) << 16; return v.f; }
__device__ inline us f2bf(float x) {
    union { float f; u32 i; } v; v.f = x;
    u32 r = v.i + 0x7FFFu + ((v.i >> 16) & 1u);
    return (us)(r >> 16);
}

// ---------------------------------------------------------------------------
// K0: probe key_mask storage (int32 vs u8 bool). flag=1 -> u8 storage.
// ---------------------------------------------------------------------------
__global__ void k_mask_probe(const u32* __restrict__ mw, int nwords,
                             int* __restrict__ flag)
{
    u32 any = 0;
    for (int j = blockIdx.x * blockDim.x + threadIdx.x; j < nwords;
         j += gridDim.x * blockDim.x)
        any |= mw[j] & 0xFFFFFF00u;
    if (any) atomicOr(flag, 1);
}

// ---------------------------------------------------------------------------
// K1: QKV projection. Q f32; Fk/Fv emitted bf16 (halves gather traffic).
// ---------------------------------------------------------------------------
__global__ __launch_bounds__(384) void k_qkv(
    const float* __restrict__ F, const float* __restrict__ W,
    const float* __restrict__ B,
    float* __restrict__ Q, us* __restrict__ FkB, us* __restrict__ FvB, int N)
{
    __shared__ float xL[8][CDIM];
    int row0 = blockIdx.x * 8;
    int t = threadIdx.x;
    for (int o = t; o < 8 * CDIM; o += 384) {
        int r = o >> 7, c = o & 127;
        int row = row0 + r;
        xL[r][c] = (row < N) ? F[row * CDIM + c] : 0.f;
    }
    __syncthreads();

    int e = t;  // 0..383
    const float4* W4 = (const float4*)(W + e * CDIM);
    float acc[8] = {0.f,0.f,0.f,0.f,0.f,0.f,0.f,0.f};
    #pragma unroll 8
    for (int c4 = 0; c4 < CDIM / 4; ++c4) {
        float4 w = W4[c4];
        #pragma unroll
        for (int r = 0; r < 8; ++r) {
            const float* x = &xL[r][c4 * 4];
            acc[r] += x[0]*w.x + x[1]*w.y + x[2]*w.z + x[3]*w.w;
        }
    }
    float bv = B[e];
    if (e < 128) {
        #pragma unroll
        for (int r = 0; r < 8; ++r) {
            int row = row0 + r;
            if (row < N) Q[row * CDIM + e] = acc[r] + bv;
        }
    } else if (e < 256) {
        int eo = e - 128;
        #pragma unroll
        for (int r = 0; r < 8; ++r) {
            int row = row0 + r;
            if (row < N) FkB[(size_t)row * CDIM + eo] = f2bf(acc[r] + bv);
        }
    } else {
        int eo = e - 256;
        #pragma unroll
        for (int r = 0; r < 8; ++r) {
            int row = row0 + r;
            if (row < N) FvB[(size_t)row * CDIM + eo] = f2bf(acc[r] + bv);
        }
    }
}

// ---------------------------------------------------------------------------
// K2: attention, one block (256 thr = 4 waves) per query voxel.
// Scores: MFMA qw(hi/lo).P(hi/lo in regs) + f32 q.Fk (wave 3, bf16 gather).
// Pbar:   MFMA attn(hi/lo from scL).P-hi rebuilt in registers (B-fragment
//         layout). No P plane in LDS. LDS 14656 B.
// __launch_bounds__(256,4): R7's (256,6) under-budgeted VGPRs -> ~19 dwords
// of scratch spill per thread (WRITE_SIZE 25MB->975MB). 4 waves/SIMD gives a
// 128-VGPR budget; this structure needs ~90 -> no spill (R6-verified).
// ---------------------------------------------------------------------------
__global__ __launch_bounds__(256, 4) void k_attn(
    const float* __restrict__ coords, const int* __restrict__ kidx,
    const u8* __restrict__ kmask_u8, const int* __restrict__ kmask_i32,
    const int* __restrict__ maskflag,
    const float* __restrict__ Q, const us* __restrict__ FkB,
    const us* __restrict__ FvB,
    const float* __restrict__ wk, const float* __restrict__ wv,
    const float* __restrict__ kpw, const float* __restrict__ kpb,
    float* __restrict__ CTX)
{
    // manual LDS layout (bytes):
    __shared__ __align__(16) u8 SM[14656];
    us*    qwH   = (us*)(SM);             // [8][136]  qw hi       (2176)
    us*    qwL   = (us*)(SM + 2176);      // [8][136]  qw lo       (2176)
    float* scL   = (float*)(SM + 4352);   // [8][52]               (1664)
    float* Ql    = (float*)(SM + 6016);   // [128]                 (512)
    float* rel   = (float*)(SM + 6528);   // [48][3]               (576)
    float* kpw0S = (float*)(SM + 7104);   // [128]                 (512)
    float* kpw1S = (float*)(SM + 7616);   // [128]                 (512)
    float* kpw2S = (float*)(SM + 8128);   // [128]                 (512)
    float* kpbS  = (float*)(SM + 8640);   // [128]                 (512)
    int*   idxl  = (int*)  (SM + 9152);   // [48]                  (192)
    u8*    mskl  = (u8*)   (SM + 9344);   // [48] (pad 64)         (64)
    float* Pb    = (float*)(SM + 9408);   // [8][132] Pbar         (4224)
    float* pc    = (float*)(SM + 13632);  // [2][128]              (1024)

    int n = blockIdx.x;
    int t = threadIdx.x;
    int w = t >> 6, lane = t & 63;

    // ---- phase A: indices / mask / rel / q row / kpw staging (transposed) ----
    if (t < KNBR) {
        int idx = kidx[n * KNBR + t];
        idxl[t] = idx;
        mskl[t] = maskflag[0] ? kmask_u8[n * KNBR + t]
                              : (u8)kmask_i32[n * KNBR + t];
        rel[t * 3 + 0] = coords[idx * 3 + 0] - coords[n * 3 + 0];
        rel[t * 3 + 1] = coords[idx * 3 + 1] - coords[n * 3 + 1];
        rel[t * 3 + 2] = coords[idx * 3 + 2] - coords[n * 3 + 2];
    }
    if (t < 128) {
        kpw0S[t] = kpw[t * 3 + 0];
        kpw1S[t] = kpw[t * 3 + 1];
        kpw2S[t] = kpw[t * 3 + 2];
        kpbS[t]  = kpb[t];
    } else {
        Ql[t - 128] = Q[n * CDIM + (t - 128)];
    }
    __syncthreads();

    // ---- phase B1: qw = q_h @ wk_h (f32 -> hi/lo bf16 in LDS, 8 rows) ----
    {
        int h = t >> 5, c4 = t & 31;
        const float* qh = Ql + h * DHEAD;
        float a0=0.f, a1=0.f, a2=0.f, a3=0.f;
        #pragma unroll
        for (int d = 0; d < DHEAD; ++d) {
            float q = qh[d];
            float4 wr = *(const float4*)(wk + (size_t)(h * DHEAD + d) * CDIM + c4 * 4);
            a0 += q * wr.x; a1 += q * wr.y; a2 += q * wr.z; a3 += q * wr.w;
        }
        us h0=f2bf(a0), h1=f2bf(a1), h2=f2bf(a2), h3=f2bf(a3);
        us l0=f2bf(a0-bf2f(h0)), l1=f2bf(a1-bf2f(h1)),
           l2=f2bf(a2-bf2f(h2)), l3=f2bf(a3-bf2f(h3));
        uint2 ph; ph.x = (u32)h0 | ((u32)h1 << 16); ph.y = (u32)h2 | ((u32)h3 << 16);
        uint2 pl; pl.x = (u32)l0 | ((u32)l1 << 16); pl.y = (u32)l2 | ((u32)l3 << 16);
        *(uint2*)&qwH[h * 136 + c4 * 4] = ph;
        *(uint2*)&qwL[h * 136 + c4 * 4] = pl;
    }

    // ---- phase B2: waves 0-2: P score-B-fragments in registers;
    //                wave 3: exact f32 q.Fk partial scores (bf16 gather) ----
    union U8 { bf16x8 v; u32 wd[4]; };
    U8 BH[4], BL[4];
    if (w < 3) {
        int kk = w * 16 + (lane & 15);        // P row this lane owns
        int cb0 = (lane >> 4) * 8;            // c-chunk base
        float r0 = rel[kk * 3], r1 = rel[kk * 3 + 1], r2 = rel[kk * 3 + 2];
        #pragma unroll
        for (int s = 0; s < 4; ++s) {
            int cb = cb0 + s * 32;
            float4 x0 = *(const float4*)&kpw0S[cb], x1 = *(const float4*)&kpw0S[cb + 4];
            float4 y0 = *(const float4*)&kpw1S[cb], y1 = *(const float4*)&kpw1S[cb + 4];
            float4 z0 = *(const float4*)&kpw2S[cb], z1 = *(const float4*)&kpw2S[cb + 4];
            float4 b0 = *(const float4*)&kpbS[cb],  b1 = *(const float4*)&kpbS[cb + 4];
            float p[8];
            p[0] = fmaxf(b0.x + r0*x0.x + r1*y0.x + r2*z0.x, 0.f);
            p[1] = fmaxf(b0.y + r0*x0.y + r1*y0.y + r2*z0.y, 0.f);
            p[2] = fmaxf(b0.z + r0*x0.z + r1*y0.z + r2*z0.z, 0.f);
            p[3] = fmaxf(b0.w + r0*x0.w + r1*y0.w + r2*z0.w, 0.f);
            p[4] = fmaxf(b1.x + r0*x1.x + r1*y1.x + r2*z1.x, 0.f);
            p[5] = fmaxf(b1.y + r0*x1.y + r1*y1.y + r2*z1.y, 0.f);
            p[6] = fmaxf(b1.z + r0*x1.z + r1*y1.z + r2*z1.z, 0.f);
            p[7] = fmaxf(b1.w + r0*x1.w + r1*y1.w + r2*z1.w, 0.f);
            #pragma unroll
            for (int j = 0; j < 4; ++j) {
                us hA = f2bf(p[2*j]), hB = f2bf(p[2*j+1]);
                BH[s].wd[j] = (u32)hA | ((u32)hB << 16);
                us lA = f2bf(p[2*j]   - bf2f(hA));
                us lB = f2bf(p[2*j+1] - bf2f(hB));
                BL[s].wd[j] = (u32)lA | ((u32)lB << 16);
            }
        }
    } else {
        #pragma unroll
        for (int i = 0; i < 6; ++i) {
            int o = lane * 6 + i;             // 384 = 48 k x 8 h
            int k = o >> 3, h = o & 7;
            const float* qh = Ql + h * DHEAD;
            const uint4* fk = (const uint4*)(FkB + (size_t)idxl[k] * CDIM + h * DHEAD);
            uint4 fa = fk[0], fb = fk[1];
            float s = qh[0]*blo32(fa.x) + qh[1]*bhi32(fa.x)
                    + qh[2]*blo32(fa.y) + qh[3]*bhi32(fa.y)
                    + qh[4]*blo32(fa.z) + qh[5]*bhi32(fa.z)
                    + qh[6]*blo32(fa.w) + qh[7]*bhi32(fa.w)
                    + qh[8]*blo32(fb.x) + qh[9]*bhi32(fb.x)
                    + qh[10]*blo32(fb.y) + qh[11]*bhi32(fb.y)
                    + qh[12]*blo32(fb.z) + qh[13]*bhi32(fb.z)
                    + qh[14]*blo32(fb.w) + qh[15]*bhi32(fb.w);
            scL[h * 52 + k] = s;
        }
    }
    __syncthreads();

    // ---- phase C: MFMA scores (waves 0-2), A=qw from LDS (rows>=8 zero) ----
    if (w < 3) {
        f32x4 acc = {0.f, 0.f, 0.f, 0.f};
        int arow = lane & 15;
        int ko = (lane >> 4) * 8;
        bool aval = arow < 8;
        bf16x8 zz = {0,0,0,0,0,0,0,0};
        #pragma unroll
        for (int s = 0; s < 4; ++s) {
            int c0 = s * 32 + ko;
            bf16x8 ah = aval ? *(const bf16x8*)(qwH + arow * 136 + c0) : zz;
            bf16x8 al = aval ? *(const bf16x8*)(qwL + arow * 136 + c0) : zz;
            acc = __builtin_amdgcn_mfma_f32_16x16x32_bf16(ah, BH[s].v, acc, 0, 0, 0);
            acc = __builtin_amdgcn_mfma_f32_16x16x32_bf16(ah, BL[s].v, acc, 0, 0, 0);
            acc = __builtin_amdgcn_mfma_f32_16x16x32_bf16(al, BH[s].v, acc, 0, 0, 0);
        }
        // combine: D col=lane&15 -> kk, row=(lane>>4)*4+j -> h (rows 0-7 valid)
        if (lane < 32) {
            int kk = w * 16 + (lane & 15);
            int rb = (lane >> 4) * 4;
            u8 mk = mskl[kk];
            #pragma unroll
            for (int j = 0; j < 4; ++j) {
                int h = rb + j;
                float s = acc[j] + scL[h * 52 + kk];
                scL[h * 52 + kk] = mk ? -1e30f : s * 0.25f;
            }
        }
    }
    __syncthreads();

    // ---- phase D: softmax (32 lanes per head) ----
    {
        int h = t >> 5, l32 = t & 31;
        float* sc = scL + h * 52;
        float v0 = sc[l32];
        float v1 = (l32 < KNBR - 32) ? sc[l32 + 32] : -1e30f;
        float m = fmaxf(v0, v1);
        #pragma unroll
        for (int off = 16; off >= 1; off >>= 1)
            m = fmaxf(m, __shfl_xor(m, off, 32));
        float e0 = __expf(v0 - m);
        float e1 = (l32 < KNBR - 32) ? __expf(v1 - m) : 0.f;
        float s = e0 + e1;
        #pragma unroll
        for (int off = 16; off >= 1; off >>= 1)
            s += __shfl_xor(s, off, 32);
        float inv = 1.f / s;
        sc[l32] = e0 * inv;
        if (l32 < KNBR - 32) sc[l32 + 32] = e1 * inv;
    }
    __syncthreads();

    // ---- phase E: Pbar via MFMA. A=attn hi/lo (from scL), B=P-hi rebuilt
    //      in registers in B-fragment layout. All 4 waves, 2 c-tiles each. ----
    {
        bf16x8 AH[2], AL[2];
        int arow = lane & 15;
        bool av = arow < 8;
        #pragma unroll
        for (int st = 0; st < 2; ++st) {
            int k0 = (lane >> 4) * 8 + st * 32;
            float pr[8];
            if (av && k0 < KNBR) {
                float4 s0 = *(const float4*)&scL[arow * 52 + k0];
                float4 s1 = *(const float4*)&scL[arow * 52 + k0 + 4];
                pr[0]=s0.x; pr[1]=s0.y; pr[2]=s0.z; pr[3]=s0.w;
                pr[4]=s1.x; pr[5]=s1.y; pr[6]=s1.z; pr[7]=s1.w;
            } else {
                #pragma unroll
                for (int j = 0; j < 8; ++j) pr[j] = 0.f;
            }
            U8 ah, al;
            #pragma unroll
            for (int j = 0; j < 4; ++j) {
                us hA = f2bf(pr[2*j]), hB = f2bf(pr[2*j+1]);
                ah.wd[j] = (u32)hA | ((u32)hB << 16);
                us lA = f2bf(pr[2*j]   - bf2f(hA));
                us lB = f2bf(pr[2*j+1] - bf2f(hB));
                al.wd[j] = (u32)lA | ((u32)lB << 16);
            }
            AH[st] = ah.v; AL[st] = al.v;
        }
        #pragma unroll
        for (int ct = 0; ct < 2; ++ct) {
            int c = w * 32 + ct * 16 + (lane & 15);
            float w0 = kpw0S[c], w1 = kpw1S[c], w2 = kpw2S[c], bb = kpbS[c];
            f32x4 acc = {0.f, 0.f, 0.f, 0.f};
            #pragma unroll
            for (int st = 0; st < 2; ++st) {
                int k0 = (lane >> 4) * 8 + st * 32;
                U8 bh;
                if (k0 < KNBR) {
                    #pragma unroll
                    for (int j = 0; j < 4; ++j) {
                        const float* ra = rel + (k0 + 2*j) * 3;
                        const float* rb = rel + (k0 + 2*j + 1) * 3;
                        float pa = fmaxf(bb + ra[0]*w0 + ra[1]*w1 + ra[2]*w2, 0.f);
                        float pb = fmaxf(bb + rb[0]*w0 + rb[1]*w1 + rb[2]*w2, 0.f);
                        bh.wd[j] = (u32)f2bf(pa) | ((u32)f2bf(pb) << 16);
                    }
                } else {
                    bh.wd[0]=bh.wd[1]=bh.wd[2]=bh.wd[3]=0u;
                }
                acc = __builtin_amdgcn_mfma_f32_16x16x32_bf16(AH[st], bh.v, acc, 0, 0, 0);
                acc = __builtin_amdgcn_mfma_f32_16x16x32_bf16(AL[st], bh.v, acc, 0, 0, 0);
            }
            // D: col=lane&15 (c), row=(lane>>4)*4+j (h; rows 0-7 valid)
            if (lane < 32) {
                int rb2 = (lane >> 4) * 4;
                #pragma unroll
                for (int j = 0; j < 4; ++j)
                    Pb[(rb2 + j) * 132 + c] = acc[j];
            }
        }
    }
    __syncthreads();

    // ---- phase F: ctx = attn @ Fv (bf16 gather) + Pbar . wv ----
    {
        int c = t & 127, half = t >> 7;
        int h = c >> 4;
        const float* sc = scL + h * 52;
        float accF = 0.f;
        #pragma unroll 4
        for (int kk = 0; kk < 24; ++kk) {
            int k = half * 24 + kk;
            accF += sc[k] * bf2f(FvB[(size_t)idxl[k] * CDIM + c]);
        }
        const float4* wr = (const float4*)(wv + (size_t)c * CDIM) + half * 16;
        const float4* pb4 = (const float4*)(Pb + h * 132) + half * 16;
        #pragma unroll 4
        for (int j = 0; j < 16; ++j) {
            float4 wq = wr[j], p = pb4[j];
            accF += wq.x*p.x + wq.y*p.y + wq.z*p.z + wq.w*p.w;
        }
        pc[half * 128 + c] = accF;
    }
    __syncthreads();
    if (t < CDIM) CTX[n * CDIM + t] = pc[t] + pc[128 + t];
}

// ---------------------------------------------------------------------------
// K3/K6: 128->128 GEMM + bias (+ optional residual) + LayerNorm (+ opt relu)
// ---------------------------------------------------------------------------
__global__ __launch_bounds__(256) void k_proj_ln(
    const float* __restrict__ X, const float* __restrict__ RES,
    const float* __restrict__ W, const float* __restrict__ B,
    const float* __restrict__ G, const float* __restrict__ LB,
    float* __restrict__ OUT, int N, int relu_out)
{
    __shared__ float xL[16][CDIM];
    __shared__ float aL[16][CDIM + 4];
    __shared__ float mu[16], rs[16];
    int row0 = blockIdx.x * 16;
    int t = threadIdx.x;
    for (int o = t; o < 16 * CDIM; o += 256) {
        int r = o >> 7, c = o & 127;
        int row = row0 + r;
        xL[r][c] = (row < N) ? X[row * CDIM + c] : 0.f;
    }
    __syncthreads();

    int e = t & 127, rh = t >> 7;
    const float4* W4 = (const float4*)(W + e * CDIM);
    float acc[8] = {0.f,0.f,0.f,0.f,0.f,0.f,0.f,0.f};
    #pragma unroll 8
    for (int c4 = 0; c4 < CDIM / 4; ++c4) {
        float4 w = W4[c4];
        #pragma unroll
        for (int i = 0; i < 8; ++i) {
            const float* x = &xL[rh * 8 + i][c4 * 4];
            acc[i] += x[0]*w.x + x[1]*w.y + x[2]*w.z + x[3]*w.w;
        }
    }
    float bv = B[e];
    #pragma unroll
    for (int i = 0; i < 8; ++i) {
        int r = rh * 8 + i, row = row0 + r;
        float a = acc[i] + bv;
        if (RES != nullptr && row < N) a += RES[row * CDIM + e];
        aL[r][e] = a;
    }
    __syncthreads();

    {
        int r = t >> 4, j = t & 15;
        float s = 0.f;
        #pragma unroll
        for (int jj = 0; jj < 8; ++jj) s += aL[r][j * 8 + jj];
        #pragma unroll
        for (int off = 8; off >= 1; off >>= 1) s += __shfl_xor(s, off, 16);
        float mean = s * (1.f / 128.f);
        float v = 0.f;
        #pragma unroll
        for (int jj = 0; jj < 8; ++jj) {
            float d = aL[r][j * 8 + jj] - mean; v += d * d;
        }
        #pragma unroll
        for (int off = 8; off >= 1; off >>= 1) v += __shfl_xor(v, off, 16);
        if (j == 0) { mu[r] = mean; rs[r] = rsqrtf(v * (1.f / 128.f) + 1e-5f); }
    }
    __syncthreads();

    for (int o = t; o < 16 * CDIM; o += 256) {
        int r = o >> 7, c = o & 127;
        int row = row0 + r;
        if (row < N) {
            float y = (aL[r][c] - mu[r]) * rs[r] * G[c] + LB[c];
            if (relu_out) y = fmaxf(y, 0.f);
            OUT[row * CDIM + c] = y;
        }
    }
}

// ---------------------------------------------------------------------------
// K4: ff1: hid = relu(x1 @ W1^T + b1), 128 -> 256.
// ---------------------------------------------------------------------------
__global__ __launch_bounds__(256) void k_ff1(
    const float* __restrict__ X, const float* __restrict__ W,
    const float* __restrict__ B, float* __restrict__ HID, int N)
{
    __shared__ float xL[8][CDIM];
    int row0 = blockIdx.x * 8;
    int t = threadIdx.x;
    for (int o = t; o < 8 * CDIM; o += 256) {
        int r = o >> 7, c = o & 127;
        int row = row0 + r;
        xL[r][c] = (row < N) ? X[row * CDIM + c] : 0.f;
    }
    __syncthreads();

    int e = t;
    const float4* W4 = (const float4*)(W + e * CDIM);
    float acc[8] = {0.f,0.f,0.f,0.f,0.f,0.f,0.f,0.f};
    #pragma unroll 8
    for (int c4 = 0; c4 < CDIM / 4; ++c4) {
        float4 w = W4[c4];
        #pragma unroll
        for (int r = 0; r < 8; ++r) {
            const float* x = &xL[r][c4 * 4];
            acc[r] += x[0]*w.x + x[1]*w.y + x[2]*w.z + x[3]*w.w;
        }
    }
    float bv = B[e];
    #pragma unroll
    for (int r = 0; r < 8; ++r) {
        int row = row0 + r;
        if (row < N) HID[row * FFDIM + e] = fmaxf(acc[r] + bv, 0.f);
    }
}

// ---------------------------------------------------------------------------
// K5: x2 = LN(x1 + hid @ W2^T + b2), 256 -> 128.
// ---------------------------------------------------------------------------
__global__ __launch_bounds__(256) void k_ff2_ln(
    const float* __restrict__ HID, const float* __restrict__ RES,
    const float* __restrict__ W, const float* __restrict__ B,
    const float* __restrict__ G, const float* __restrict__ LB,
    float* __restrict__ OUT, int N)
{
    __shared__ float xL[16][FFDIM];
    __shared__ float aL[16][CDIM + 4];
    __shared__ float mu[16], rs[16];
    int row0 = blockIdx.x * 16;
    int t = threadIdx.x;
    for (int o = t; o < 16 * FFDIM; o += 256) {
        int r = o >> 8, c = o & 255;
        int row = row0 + r;
        xL[r][c] = (row < N) ? HID[row * FFDIM + c] : 0.f;
    }
    __syncthreads();

    int e = t & 127, rh = t >> 7;
    const float4* W4 = (const float4*)(W + e * FFDIM);
    float acc[8] = {0.f,0.f,0.f,0.f,0.f,0.f,0.f,0.f};
    #pragma unroll 8
    for (int c4 = 0; c4 < FFDIM / 4; ++c4) {
        float4 w = W4[c4];
        #pragma unroll
        for (int i = 0; i < 8; ++i) {
            const float* x = &xL[rh * 8 + i][c4 * 4];
            acc[i] += x[0]*w.x + x[1]*w.y + x[2]*w.z + x[3]*w.w;
        }
    }
    float bv = B[e];
    #pragma unroll
    for (int i = 0; i < 8; ++i) {
        int r = rh * 8 + i, row = row0 + r;
        float a = acc[i] + bv;
        if (row < N) a += RES[row * CDIM + e];
        aL[r][e] = a;
    }
    __syncthreads();

    {
        int r = t >> 4, j = t & 15;
        float s = 0.f;
        #pragma unroll
        for (int jj = 0; jj < 8; ++jj) s += aL[r][j * 8 + jj];
        #pragma unroll
        for (int off = 8; off >= 1; off >>= 1) s += __shfl_xor(s, off, 16);
        float mean = s * (1.f / 128.f);
        float v = 0.f;
        #pragma unroll
        for (int jj = 0; jj < 8; ++jj) {
            float d = aL[r][j * 8 + jj] - mean; v += d * d;
        }
        #pragma unroll
        for (int off = 8; off >= 1; off >>= 1) v += __shfl_xor(v, off, 16);
        if (j == 0) { mu[r] = mean; rs[r] = rsqrtf(v * (1.f / 128.f) + 1e-5f); }
    }
    __syncthreads();

    for (int o = t; o < 16 * CDIM; o += 256) {
        int r = o >> 7, c = o & 127;
        int row = row0 + r;
        if (row < N)
            OUT[row * CDIM + c] = (aL[r][c] - mu[r]) * rs[r] * G[c] + LB[c];
    }
}

// ---------------------------------------------------------------------------
extern "C" void kernel_launch(void* const* d_in, const int* in_sizes, int n_in,
                              void* d_out, int out_size, void* d_ws, size_t ws_size,
                              hipStream_t stream)
{
    const float* F      = (const float*)d_in[0];
    const float* coords = (const float*)d_in[1];
    const int*   kidx   = (const int*)d_in[2];
    const void*  kmask  = d_in[3];
    const float* ipw    = (const float*)d_in[4];
    const float* ipb    = (const float*)d_in[5];
    const float* opw    = (const float*)d_in[6];
    const float* opb    = (const float*)d_in[7];
    const float* kpw    = (const float*)d_in[8];
    const float* kpb    = (const float*)d_in[9];
    const float* ln1g   = (const float*)d_in[10];
    const float* ln1b   = (const float*)d_in[11];
    const float* ln2g   = (const float*)d_in[12];
    const float* ln2b   = (const float*)d_in[13];
    const float* w1     = (const float*)d_in[14];
    const float* b1     = (const float*)d_in[15];
    const float* w2     = (const float*)d_in[16];
    const float* b2     = (const float*)d_in[17];
    const float* ow     = (const float*)d_in[18];
    const float* ob     = (const float*)d_in[19];
    const float* ln3g   = (const float*)d_in[20];
    const float* ln3b   = (const float*)d_in[21];

    int N = in_sizes[0] / CDIM;
    size_t NC = (size_t)N * CDIM;

    float* ws  = (float*)d_ws;
    // layout (floats):
    //   [0,   NC)   Q  (later X1)
    //   [NC,  1.5NC) FkB (bf16)  } HID = [NC,3NC) after attention
    //   [1.5NC,2NC)  FvB (bf16)  }
    //   [2NC, 3NC)  CTX (dead after proj_ln1)
    //   [3NC, 4NC)  X2
    //   [4NC]       mflag
    float* Q    = ws;
    us*    FkB  = (us*)(ws + NC);
    us*    FvB  = (us*)(ws + NC) + NC;
    float* CTX  = ws + 2 * NC;
    float* X1   = Q;
    float* HID  = ws + NC;
    float* X2   = ws + 3 * NC;
    int*   mflag = (int*)(ws + 4 * NC);

    const float* wk = ipw + CDIM * CDIM;
    const float* wv = ipw + 2 * CDIM * CDIM;

    hipMemsetAsync(mflag, 0, sizeof(int), stream);
    int nwords = (N * KNBR) / 4;
    k_mask_probe<<<256, 256, 0, stream>>>((const u32*)kmask, nwords, mflag);

    k_qkv<<<(N + 7) / 8, 384, 0, stream>>>(F, ipw, ipb, Q, FkB, FvB, N);
    k_attn<<<N, 256, 0, stream>>>(coords, kidx, (const u8*)kmask,
                                  (const int*)kmask, mflag, Q, FkB, FvB,
                                  wk, wv, kpw, kpb, CTX);
    k_proj_ln<<<(N + 15) / 16, 256, 0, stream>>>(CTX, F, opw, opb,
                                                 ln1g, ln1b, X1, N, 0);
    k_ff1<<<(N + 7) / 8, 256, 0, stream>>>(X1, w1, b1, HID, N);
    k_ff2_ln<<<(N + 15) / 16, 256, 0, stream>>>(HID, X1, w2, b2,
                                                ln2g, ln2b, X2, N);
    k_proj_ln<<<(N + 15) / 16, 256, 0, stream>>>(X2, nullptr, ow, ob,
                                                 ln3g, ln3b, (float*)d_out, N, 1);
}

// Round 9
// 1120.896 us; speedup vs baseline: 1.1835x; 1.0312x over previous
//
#include <hip/hip_runtime.h>
#include <stdint.h>

typedef unsigned char u8;
typedef unsigned short us;
typedef unsigned int u32;

#define CDIM  128
#define KNBR  48
#define HEADS 8
#define DHEAD 16
#define FFDIM 256

using bf16x8 = __attribute__((ext_vector_type(8))) short;  // 8 bf16 (4 VGPRs)
using f32x4  = __attribute__((ext_vector_type(4))) float;  // 4 fp32

__device__ inline float blo32(u32 u) { union { u32 i; float f; } v; v.i = u << 16; return v.f; }
__device__ inline float bhi32(u32 u) { union { u32 i; float f; } v; v.i = u & 0xFFFF0000u; return v.f; }
__device__ inline float bf2f(us u) { union { u32 i; float f; } v; v.i = ((u32)u) << 16; return v.f; }
__device__ inline us f2bf(float x) {
    union { float f; u32 i; } v; v.f = x;
    u32 r = v.i + 0x7FFFu + ((v.i >> 16) & 1u);
    return (us)(r >> 16);
}
// HW packed f32x2 -> bf16x2 (RNE), one instruction (gfx950; no builtin).
__device__ inline u32 cvtpk(float a, float b) {
    u32 r;
    asm("v_cvt_pk_bf16_f32 %0, %1, %2" : "=v"(r) : "v"(a), "v"(b));
    return r;
}

// ---------------------------------------------------------------------------
// K0: probe key_mask storage (int32 vs u8 bool). flag=1 -> u8 storage.
// ---------------------------------------------------------------------------
__global__ void k_mask_probe(const u32* __restrict__ mw, int nwords,
                             int* __restrict__ flag)
{
    u32 any = 0;
    for (int j = blockIdx.x * blockDim.x + threadIdx.x; j < nwords;
         j += gridDim.x * blockDim.x)
        any |= mw[j] & 0xFFFFFF00u;
    if (any) atomicOr(flag, 1);
}

// ---------------------------------------------------------------------------
// K1: QKV projection. Q f32; Fk/Fv emitted bf16 (halves gather traffic).
// ---------------------------------------------------------------------------
__global__ __launch_bounds__(384) void k_qkv(
    const float* __restrict__ F, const float* __restrict__ W,
    const float* __restrict__ B,
    float* __restrict__ Q, us* __restrict__ FkB, us* __restrict__ FvB, int N)
{
    __shared__ float xL[8][CDIM];
    int row0 = blockIdx.x * 8;
    int t = threadIdx.x;
    for (int o = t; o < 8 * CDIM; o += 384) {
        int r = o >> 7, c = o & 127;
        int row = row0 + r;
        xL[r][c] = (row < N) ? F[row * CDIM + c] : 0.f;
    }
    __syncthreads();

    int e = t;  // 0..383
    const float4* W4 = (const float4*)(W + e * CDIM);
    float acc[8] = {0.f,0.f,0.f,0.f,0.f,0.f,0.f,0.f};
    #pragma unroll 8
    for (int c4 = 0; c4 < CDIM / 4; ++c4) {
        float4 w = W4[c4];
        #pragma unroll
        for (int r = 0; r < 8; ++r) {
            const float* x = &xL[r][c4 * 4];
            acc[r] += x[0]*w.x + x[1]*w.y + x[2]*w.z + x[3]*w.w;
        }
    }
    float bv = B[e];
    if (e < 128) {
        #pragma unroll
        for (int r = 0; r < 8; ++r) {
            int row = row0 + r;
            if (row < N) Q[row * CDIM + e] = acc[r] + bv;
        }
    } else if (e < 256) {
        int eo = e - 128;
        #pragma unroll
        for (int r = 0; r < 8; ++r) {
            int row = row0 + r;
            if (row < N) FkB[(size_t)row * CDIM + eo] = f2bf(acc[r] + bv);
        }
    } else {
        int eo = e - 256;
        #pragma unroll
        for (int r = 0; r < 8; ++r) {
            int row = row0 + r;
            if (row < N) FvB[(size_t)row * CDIM + eo] = f2bf(acc[r] + bv);
        }
    }
}

// ---------------------------------------------------------------------------
// K2: attention, one block (256 thr = 4 waves) per query voxel.
// Same structure as R8 (MFMA scores + MFMA Pbar, bf16 gathers, no P in LDS)
// but ALL f32->bf16 packing now uses HW v_cvt_pk_bf16_f32 (1 inst per pair
// vs ~24 for the software RNE path) — packing was ~1/3 of VALU work.
// __launch_bounds__(256,4): (256,6) spills (R7: WRITE 975MB). LDS 14656 B.
// ---------------------------------------------------------------------------
__global__ __launch_bounds__(256, 4) void k_attn(
    const float* __restrict__ coords, const int* __restrict__ kidx,
    const u8* __restrict__ kmask_u8, const int* __restrict__ kmask_i32,
    const int* __restrict__ maskflag,
    const float* __restrict__ Q, const us* __restrict__ FkB,
    const us* __restrict__ FvB,
    const float* __restrict__ wk, const float* __restrict__ wv,
    const float* __restrict__ kpw, const float* __restrict__ kpb,
    float* __restrict__ CTX)
{
    // manual LDS layout (bytes):
    __shared__ __align__(16) u8 SM[14656];
    us*    qwH   = (us*)(SM);             // [8][136]  qw hi       (2176)
    us*    qwL   = (us*)(SM + 2176);      // [8][136]  qw lo       (2176)
    float* scL   = (float*)(SM + 4352);   // [8][52]               (1664)
    float* Ql    = (float*)(SM + 6016);   // [128]                 (512)
    float* rel   = (float*)(SM + 6528);   // [48][3]               (576)
    float* kpw0S = (float*)(SM + 7104);   // [128]                 (512)
    float* kpw1S = (float*)(SM + 7616);   // [128]                 (512)
    float* kpw2S = (float*)(SM + 8128);   // [128]                 (512)
    float* kpbS  = (float*)(SM + 8640);   // [128]                 (512)
    int*   idxl  = (int*)  (SM + 9152);   // [48]                  (192)
    u8*    mskl  = (u8*)   (SM + 9344);   // [48] (pad 64)         (64)
    float* Pb    = (float*)(SM + 9408);   // [8][132] Pbar         (4224)
    float* pc    = (float*)(SM + 13632);  // [2][128]              (1024)

    int n = blockIdx.x;
    int t = threadIdx.x;
    int w = t >> 6, lane = t & 63;

    // ---- phase A: indices / mask / rel / q row / kpw staging (transposed) ----
    if (t < KNBR) {
        int idx = kidx[n * KNBR + t];
        idxl[t] = idx;
        mskl[t] = maskflag[0] ? kmask_u8[n * KNBR + t]
                              : (u8)kmask_i32[n * KNBR + t];
        rel[t * 3 + 0] = coords[idx * 3 + 0] - coords[n * 3 + 0];
        rel[t * 3 + 1] = coords[idx * 3 + 1] - coords[n * 3 + 1];
        rel[t * 3 + 2] = coords[idx * 3 + 2] - coords[n * 3 + 2];
    }
    if (t < 128) {
        kpw0S[t] = kpw[t * 3 + 0];
        kpw1S[t] = kpw[t * 3 + 1];
        kpw2S[t] = kpw[t * 3 + 2];
        kpbS[t]  = kpb[t];
    } else {
        Ql[t - 128] = Q[n * CDIM + (t - 128)];
    }
    __syncthreads();

    // ---- phase B1: qw = q_h @ wk_h (f32 -> hi/lo bf16 in LDS, 8 rows) ----
    {
        int h = t >> 5, c4 = t & 31;
        const float* qh = Ql + h * DHEAD;
        float a0=0.f, a1=0.f, a2=0.f, a3=0.f;
        #pragma unroll
        for (int d = 0; d < DHEAD; ++d) {
            float q = qh[d];
            float4 wr = *(const float4*)(wk + (size_t)(h * DHEAD + d) * CDIM + c4 * 4);
            a0 += q * wr.x; a1 += q * wr.y; a2 += q * wr.z; a3 += q * wr.w;
        }
        uint2 ph, pl;
        ph.x = cvtpk(a0, a1);
        ph.y = cvtpk(a2, a3);
        pl.x = cvtpk(a0 - blo32(ph.x), a1 - bhi32(ph.x));
        pl.y = cvtpk(a2 - blo32(ph.y), a3 - bhi32(ph.y));
        *(uint2*)&qwH[h * 136 + c4 * 4] = ph;
        *(uint2*)&qwL[h * 136 + c4 * 4] = pl;
    }

    // ---- phase B2: waves 0-2: P score-B-fragments in registers;
    //                wave 3: exact f32 q.Fk partial scores (bf16 gather) ----
    union U8 { bf16x8 v; u32 wd[4]; };
    U8 BH[4], BL[4];
    if (w < 3) {
        int kk = w * 16 + (lane & 15);        // P row this lane owns
        int cb0 = (lane >> 4) * 8;            // c-chunk base
        float r0 = rel[kk * 3], r1 = rel[kk * 3 + 1], r2 = rel[kk * 3 + 2];
        #pragma unroll
        for (int s = 0; s < 4; ++s) {
            int cb = cb0 + s * 32;
            float4 x0 = *(const float4*)&kpw0S[cb], x1 = *(const float4*)&kpw0S[cb + 4];
            float4 y0 = *(const float4*)&kpw1S[cb], y1 = *(const float4*)&kpw1S[cb + 4];
            float4 z0 = *(const float4*)&kpw2S[cb], z1 = *(const float4*)&kpw2S[cb + 4];
            float4 b0 = *(const float4*)&kpbS[cb],  b1 = *(const float4*)&kpbS[cb + 4];
            float p[8];
            p[0] = fmaxf(b0.x + r0*x0.x + r1*y0.x + r2*z0.x, 0.f);
            p[1] = fmaxf(b0.y + r0*x0.y + r1*y0.y + r2*z0.y, 0.f);
            p[2] = fmaxf(b0.z + r0*x0.z + r1*y0.z + r2*z0.z, 0.f);
            p[3] = fmaxf(b0.w + r0*x0.w + r1*y0.w + r2*z0.w, 0.f);
            p[4] = fmaxf(b1.x + r0*x1.x + r1*y1.x + r2*z1.x, 0.f);
            p[5] = fmaxf(b1.y + r0*x1.y + r1*y1.y + r2*z1.y, 0.f);
            p[6] = fmaxf(b1.z + r0*x1.z + r1*y1.z + r2*z1.z, 0.f);
            p[7] = fmaxf(b1.w + r0*x1.w + r1*y1.w + r2*z1.w, 0.f);
            #pragma unroll
            for (int j = 0; j < 4; ++j) {
                u32 hh = cvtpk(p[2*j], p[2*j+1]);
                BH[s].wd[j] = hh;
                BL[s].wd[j] = cvtpk(p[2*j] - blo32(hh), p[2*j+1] - bhi32(hh));
            }
        }
    } else {
        #pragma unroll
        for (int i = 0; i < 6; ++i) {
            int o = lane * 6 + i;             // 384 = 48 k x 8 h
            int k = o >> 3, h = o & 7;
            const float* qh = Ql + h * DHEAD;
            const uint4* fk = (const uint4*)(FkB + (size_t)idxl[k] * CDIM + h * DHEAD);
            uint4 fa = fk[0], fb = fk[1];
            float s = qh[0]*blo32(fa.x) + qh[1]*bhi32(fa.x)
                    + qh[2]*blo32(fa.y) + qh[3]*bhi32(fa.y)
                    + qh[4]*blo32(fa.z) + qh[5]*bhi32(fa.z)
                    + qh[6]*blo32(fa.w) + qh[7]*bhi32(fa.w)
                    + qh[8]*blo32(fb.x) + qh[9]*bhi32(fb.x)
                    + qh[10]*blo32(fb.y) + qh[11]*bhi32(fb.y)
                    + qh[12]*blo32(fb.z) + qh[13]*bhi32(fb.z)
                    + qh[14]*blo32(fb.w) + qh[15]*bhi32(fb.w);
            scL[h * 52 + k] = s;
        }
    }
    __syncthreads();

    // ---- phase C: MFMA scores (waves 0-2), A=qw from LDS (rows>=8 zero) ----
    if (w < 3) {
        f32x4 acc = {0.f, 0.f, 0.f, 0.f};
        int arow = lane & 15;
        int ko = (lane >> 4) * 8;
        bool aval = arow < 8;
        bf16x8 zz = {0,0,0,0,0,0,0,0};
        #pragma unroll
        for (int s = 0; s < 4; ++s) {
            int c0 = s * 32 + ko;
            bf16x8 ah = aval ? *(const bf16x8*)(qwH + arow * 136 + c0) : zz;
            bf16x8 al = aval ? *(const bf16x8*)(qwL + arow * 136 + c0) : zz;
            acc = __builtin_amdgcn_mfma_f32_16x16x32_bf16(ah, BH[s].v, acc, 0, 0, 0);
            acc = __builtin_amdgcn_mfma_f32_16x16x32_bf16(ah, BL[s].v, acc, 0, 0, 0);
            acc = __builtin_amdgcn_mfma_f32_16x16x32_bf16(al, BH[s].v, acc, 0, 0, 0);
        }
        // combine: D col=lane&15 -> kk, row=(lane>>4)*4+j -> h (rows 0-7 valid)
        if (lane < 32) {
            int kk = w * 16 + (lane & 15);
            int rb = (lane >> 4) * 4;
            u8 mk = mskl[kk];
            #pragma unroll
            for (int j = 0; j < 4; ++j) {
                int h = rb + j;
                float s = acc[j] + scL[h * 52 + kk];
                scL[h * 52 + kk] = mk ? -1e30f : s * 0.25f;
            }
        }
    }
    __syncthreads();

    // ---- phase D: softmax (32 lanes per head) ----
    {
        int h = t >> 5, l32 = t & 31;
        float* sc = scL + h * 52;
        float v0 = sc[l32];
        float v1 = (l32 < KNBR - 32) ? sc[l32 + 32] : -1e30f;
        float m = fmaxf(v0, v1);
        #pragma unroll
        for (int off = 16; off >= 1; off >>= 1)
            m = fmaxf(m, __shfl_xor(m, off, 32));
        float e0 = __expf(v0 - m);
        float e1 = (l32 < KNBR - 32) ? __expf(v1 - m) : 0.f;
        float s = e0 + e1;
        #pragma unroll
        for (int off = 16; off >= 1; off >>= 1)
            s += __shfl_xor(s, off, 32);
        float inv = 1.f / s;
        sc[l32] = e0 * inv;
        if (l32 < KNBR - 32) sc[l32 + 32] = e1 * inv;
    }
    __syncthreads();

    // ---- phase E: Pbar via MFMA. A=attn hi/lo (from scL), B=P-hi rebuilt
    //      in registers in B-fragment layout. All 4 waves, 2 c-tiles each. ----
    {
        bf16x8 AH[2], AL[2];
        int arow = lane & 15;
        bool av = arow < 8;
        #pragma unroll
        for (int st = 0; st < 2; ++st) {
            int k0 = (lane >> 4) * 8 + st * 32;
            float pr[8];
            if (av && k0 < KNBR) {
                float4 s0 = *(const float4*)&scL[arow * 52 + k0];
                float4 s1 = *(const float4*)&scL[arow * 52 + k0 + 4];
                pr[0]=s0.x; pr[1]=s0.y; pr[2]=s0.z; pr[3]=s0.w;
                pr[4]=s1.x; pr[5]=s1.y; pr[6]=s1.z; pr[7]=s1.w;
            } else {
                #pragma unroll
                for (int j = 0; j < 8; ++j) pr[j] = 0.f;
            }
            U8 ah, al;
            #pragma unroll
            for (int j = 0; j < 4; ++j) {
                u32 hh = cvtpk(pr[2*j], pr[2*j+1]);
                ah.wd[j] = hh;
                al.wd[j] = cvtpk(pr[2*j] - blo32(hh), pr[2*j+1] - bhi32(hh));
            }
            AH[st] = ah.v; AL[st] = al.v;
        }
        #pragma unroll
        for (int ct = 0; ct < 2; ++ct) {
            int c = w * 32 + ct * 16 + (lane & 15);
            float w0 = kpw0S[c], w1 = kpw1S[c], w2 = kpw2S[c], bb = kpbS[c];
            f32x4 acc = {0.f, 0.f, 0.f, 0.f};
            #pragma unroll
            for (int st = 0; st < 2; ++st) {
                int k0 = (lane >> 4) * 8 + st * 32;
                U8 bh;
                if (k0 < KNBR) {
                    #pragma unroll
                    for (int j = 0; j < 4; ++j) {
                        const float* ra = rel + (k0 + 2*j) * 3;
                        const float* rb = rel + (k0 + 2*j + 1) * 3;
                        float pa = fmaxf(bb + ra[0]*w0 + ra[1]*w1 + ra[2]*w2, 0.f);
                        float pb = fmaxf(bb + rb[0]*w0 + rb[1]*w1 + rb[2]*w2, 0.f);
                        bh.wd[j] = cvtpk(pa, pb);
                    }
                } else {
                    bh.wd[0]=bh.wd[1]=bh.wd[2]=bh.wd[3]=0u;
                }
                acc = __builtin_amdgcn_mfma_f32_16x16x32_bf16(AH[st], bh.v, acc, 0, 0, 0);
                acc = __builtin_amdgcn_mfma_f32_16x16x32_bf16(AL[st], bh.v, acc, 0, 0, 0);
            }
            // D: col=lane&15 (c), row=(lane>>4)*4+j (h; rows 0-7 valid)
            if (lane < 32) {
                int rb2 = (lane >> 4) * 4;
                #pragma unroll
                for (int j = 0; j < 4; ++j)
                    Pb[(rb2 + j) * 132 + c] = acc[j];
            }
        }
    }
    __syncthreads();

    // ---- phase F: ctx = attn @ Fv (bf16 gather) + Pbar . wv ----
    {
        int c = t & 127, half = t >> 7;
        int h = c >> 4;
        const float* sc = scL + h * 52;
        float accF = 0.f;
        #pragma unroll 4
        for (int kk = 0; kk < 24; ++kk) {
            int k = half * 24 + kk;
            accF += sc[k] * bf2f(FvB[(size_t)idxl[k] * CDIM + c]);
        }
        const float4* wr = (const float4*)(wv + (size_t)c * CDIM) + half * 16;
        const float4* pb4 = (const float4*)(Pb + h * 132) + half * 16;
        #pragma unroll 4
        for (int j = 0; j < 16; ++j) {
            float4 wq = wr[j], p = pb4[j];
            accF += wq.x*p.x + wq.y*p.y + wq.z*p.z + wq.w*p.w;
        }
        pc[half * 128 + c] = accF;
    }
    __syncthreads();
    if (t < CDIM) CTX[n * CDIM + t] = pc[t] + pc[128 + t];
}

// ---------------------------------------------------------------------------
// K3/K6: 128->128 GEMM + bias (+ optional residual) + LayerNorm (+ opt relu)
// ---------------------------------------------------------------------------
__global__ __launch_bounds__(256) void k_proj_ln(
    const float* __restrict__ X, const float* __restrict__ RES,
    const float* __restrict__ W, const float* __restrict__ B,
    const float* __restrict__ G, const float* __restrict__ LB,
    float* __restrict__ OUT, int N, int relu_out)
{
    __shared__ float xL[16][CDIM];
    __shared__ float aL[16][CDIM + 4];
    __shared__ float mu[16], rs[16];
    int row0 = blockIdx.x * 16;
    int t = threadIdx.x;
    for (int o = t; o < 16 * CDIM; o += 256) {
        int r = o >> 7, c = o & 127;
        int row = row0 + r;
        xL[r][c] = (row < N) ? X[row * CDIM + c] : 0.f;
    }
    __syncthreads();

    int e = t & 127, rh = t >> 7;
    const float4* W4 = (const float4*)(W + e * CDIM);
    float acc[8] = {0.f,0.f,0.f,0.f,0.f,0.f,0.f,0.f};
    #pragma unroll 8
    for (int c4 = 0; c4 < CDIM / 4; ++c4) {
        float4 w = W4[c4];
        #pragma unroll
        for (int i = 0; i < 8; ++i) {
            const float* x = &xL[rh * 8 + i][c4 * 4];
            acc[i] += x[0]*w.x + x[1]*w.y + x[2]*w.z + x[3]*w.w;
        }
    }
    float bv = B[e];
    #pragma unroll
    for (int i = 0; i < 8; ++i) {
        int r = rh * 8 + i, row = row0 + r;
        float a = acc[i] + bv;
        if (RES != nullptr && row < N) a += RES[row * CDIM + e];
        aL[r][e] = a;
    }
    __syncthreads();

    {
        int r = t >> 4, j = t & 15;
        float s = 0.f;
        #pragma unroll
        for (int jj = 0; jj < 8; ++jj) s += aL[r][j * 8 + jj];
        #pragma unroll
        for (int off = 8; off >= 1; off >>= 1) s += __shfl_xor(s, off, 16);
        float mean = s * (1.f / 128.f);
        float v = 0.f;
        #pragma unroll
        for (int jj = 0; jj < 8; ++jj) {
            float d = aL[r][j * 8 + jj] - mean; v += d * d;
        }
        #pragma unroll
        for (int off = 8; off >= 1; off >>= 1) v += __shfl_xor(v, off, 16);
        if (j == 0) { mu[r] = mean; rs[r] = rsqrtf(v * (1.f / 128.f) + 1e-5f); }
    }
    __syncthreads();

    for (int o = t; o < 16 * CDIM; o += 256) {
        int r = o >> 7, c = o & 127;
        int row = row0 + r;
        if (row < N) {
            float y = (aL[r][c] - mu[r]) * rs[r] * G[c] + LB[c];
            if (relu_out) y = fmaxf(y, 0.f);
            OUT[row * CDIM + c] = y;
        }
    }
}

// ---------------------------------------------------------------------------
// K4: ff1: hid = relu(x1 @ W1^T + b1), 128 -> 256.
// ---------------------------------------------------------------------------
__global__ __launch_bounds__(256) void k_ff1(
    const float* __restrict__ X, const float* __restrict__ W,
    const float* __restrict__ B, float* __restrict__ HID, int N)
{
    __shared__ float xL[8][CDIM];
    int row0 = blockIdx.x * 8;
    int t = threadIdx.x;
    for (int o = t; o < 8 * CDIM; o += 256) {
        int r = o >> 7, c = o & 127;
        int row = row0 + r;
        xL[r][c] = (row < N) ? X[row * CDIM + c] : 0.f;
    }
    __syncthreads();

    int e = t;
    const float4* W4 = (const float4*)(W + e * CDIM);
    float acc[8] = {0.f,0.f,0.f,0.f,0.f,0.f,0.f,0.f};
    #pragma unroll 8
    for (int c4 = 0; c4 < CDIM / 4; ++c4) {
        float4 w = W4[c4];
        #pragma unroll
        for (int r = 0; r < 8; ++r) {
            const float* x = &xL[r][c4 * 4];
            acc[r] += x[0]*w.x + x[1]*w.y + x[2]*w.z + x[3]*w.w;
        }
    }
    float bv = B[e];
    #pragma unroll
    for (int r = 0; r < 8; ++r) {
        int row = row0 + r;
        if (row < N) HID[row * FFDIM + e] = fmaxf(acc[r] + bv, 0.f);
    }
}

// ---------------------------------------------------------------------------
// K5: x2 = LN(x1 + hid @ W2^T + b2), 256 -> 128.
// ---------------------------------------------------------------------------
__global__ __launch_bounds__(256) void k_ff2_ln(
    const float* __restrict__ HID, const float* __restrict__ RES,
    const float* __restrict__ W, const float* __restrict__ B,
    const float* __restrict__ G, const float* __restrict__ LB,
    float* __restrict__ OUT, int N)
{
    __shared__ float xL[16][FFDIM];
    __shared__ float aL[16][CDIM + 4];
    __shared__ float mu[16], rs[16];
    int row0 = blockIdx.x * 16;
    int t = threadIdx.x;
    for (int o = t; o < 16 * FFDIM; o += 256) {
        int r = o >> 8, c = o & 255;
        int row = row0 + r;
        xL[r][c] = (row < N) ? HID[row * FFDIM + c] : 0.f;
    }
    __syncthreads();

    int e = t & 127, rh = t >> 7;
    const float4* W4 = (const float4*)(W + e * FFDIM);
    float acc[8] = {0.f,0.f,0.f,0.f,0.f,0.f,0.f,0.f};
    #pragma unroll 8
    for (int c4 = 0; c4 < FFDIM / 4; ++c4) {
        float4 w = W4[c4];
        #pragma unroll
        for (int i = 0; i < 8; ++i) {
            const float* x = &xL[rh * 8 + i][c4 * 4];
            acc[i] += x[0]*w.x + x[1]*w.y + x[2]*w.z + x[3]*w.w;
        }
    }
    float bv = B[e];
    #pragma unroll
    for (int i = 0; i < 8; ++i) {
        int r = rh * 8 + i, row = row0 + r;
        float a = acc[i] + bv;
        if (row < N) a += RES[row * CDIM + e];
        aL[r][e] = a;
    }
    __syncthreads();

    {
        int r = t >> 4, j = t & 15;
        float s = 0.f;
        #pragma unroll
        for (int jj = 0; jj < 8; ++jj) s += aL[r][j * 8 + jj];
        #pragma unroll
        for (int off = 8; off >= 1; off >>= 1) s += __shfl_xor(s, off, 16);
        float mean = s * (1.f / 128.f);
        float v = 0.f;
        #pragma unroll
        for (int jj = 0; jj < 8; ++jj) {
            float d = aL[r][j * 8 + jj] - mean; v += d * d;
        }
        #pragma unroll
        for (int off = 8; off >= 1; off >>= 1) v += __shfl_xor(v, off, 16);
        if (j == 0) { mu[r] = mean; rs[r] = rsqrtf(v * (1.f / 128.f) + 1e-5f); }
    }
    __syncthreads();

    for (int o = t; o < 16 * CDIM; o += 256) {
        int r = o >> 7, c = o & 127;
        int row = row0 + r;
        if (row < N)
            OUT[row * CDIM + c] = (aL[r][c] - mu[r]) * rs[r] * G[c] + LB[c];
    }
}

// ---------------------------------------------------------------------------
extern "C" void kernel_launch(void* const* d_in, const int* in_sizes, int n_in,
                              void* d_out, int out_size, void* d_ws, size_t ws_size,
                              hipStream_t stream)
{
    const float* F      = (const float*)d_in[0];
    const float* coords = (const float*)d_in[1];
    const int*   kidx   = (const int*)d_in[2];
    const void*  kmask  = d_in[3];
    const float* ipw    = (const float*)d_in[4];
    const float* ipb    = (const float*)d_in[5];
    const float* opw    = (const float*)d_in[6];
    const float* opb    = (const float*)d_in[7];
    const float* kpw    = (const float*)d_in[8];
    const float* kpb    = (const float*)d_in[9];
    const float* ln1g   = (const float*)d_in[10];
    const float* ln1b   = (const float*)d_in[11];
    const float* ln2g   = (const float*)d_in[12];
    const float* ln2b   = (const float*)d_in[13];
    const float* w1     = (const float*)d_in[14];
    const float* b1     = (const float*)d_in[15];
    const float* w2     = (const float*)d_in[16];
    const float* b2     = (const float*)d_in[17];
    const float* ow     = (const float*)d_in[18];
    const float* ob     = (const float*)d_in[19];
    const float* ln3g   = (const float*)d_in[20];
    const float* ln3b   = (const float*)d_in[21];

    int N = in_sizes[0] / CDIM;
    size_t NC = (size_t)N * CDIM;

    float* ws  = (float*)d_ws;
    // layout (floats):
    //   [0,   NC)   Q  (later X1)
    //   [NC,  1.5NC) FkB (bf16)  } HID = [NC,3NC) after attention
    //   [1.5NC,2NC)  FvB (bf16)  }
    //   [2NC, 3NC)  CTX (dead after proj_ln1)
    //   [3NC, 4NC)  X2
    //   [4NC]       mflag
    float* Q    = ws;
    us*    FkB  = (us*)(ws + NC);
    us*    FvB  = (us*)(ws + NC) + NC;
    float* CTX  = ws + 2 * NC;
    float* X1   = Q;
    float* HID  = ws + NC;
    float* X2   = ws + 3 * NC;
    int*   mflag = (int*)(ws + 4 * NC);

    const float* wk = ipw + CDIM * CDIM;
    const float* wv = ipw + 2 * CDIM * CDIM;

    hipMemsetAsync(mflag, 0, sizeof(int), stream);
    int nwords = (N * KNBR) / 4;
    k_mask_probe<<<256, 256, 0, stream>>>((const u32*)kmask, nwords, mflag);

    k_qkv<<<(N + 7) / 8, 384, 0, stream>>>(F, ipw, ipb, Q, FkB, FvB, N);
    k_attn<<<N, 256, 0, stream>>>(coords, kidx, (const u8*)kmask,
                                  (const int*)kmask, mflag, Q, FkB, FvB,
                                  wk, wv, kpw, kpb, CTX);
    k_proj_ln<<<(N + 15) / 16, 256, 0, stream>>>(CTX, F, opw, opb,
                                                 ln1g, ln1b, X1, N, 0);
    k_ff1<<<(N + 7) / 8, 256, 0, stream>>>(X1, w1, b1, HID, N);
    k_ff2_ln<<<(N + 15) / 16, 256, 0, stream>>>(HID, X1, w2, b2,
                                                ln2g, ln2b, X2, N);
    k_proj_ln<<<(N + 15) / 16, 256, 0, stream>>>(X2, nullptr, ow, ob,
                                                 ln3g, ln3b, (float*)d_out, N, 1);
}